// Round 1
// baseline (37.375 us; speedup 1.0000x reference)
//
#include <hip/hip_runtime.h>
#include <math.h>

#define EPSF 1e-12f

// ---------------- small float3 helpers ----------------
struct F3 { float x, y, z; };
__device__ __forceinline__ F3 mkf3(float a, float b, float c) { return {a, b, c}; }
__device__ __forceinline__ F3 operator-(F3 a, F3 b) { return {a.x - b.x, a.y - b.y, a.z - b.z}; }
__device__ __forceinline__ F3 operator+(F3 a, F3 b) { return {a.x + b.x, a.y + b.y, a.z + b.z}; }
__device__ __forceinline__ F3 operator*(float s, F3 a) { return {s * a.x, s * a.y, s * a.z}; }
__device__ __forceinline__ float dot3(F3 a, F3 b) { return a.x * b.x + a.y * b.y + a.z * b.z; }
__device__ __forceinline__ F3 cross3(F3 a, F3 b) {
    return {a.y * b.z - a.z * b.y, a.z * b.x - a.x * b.z, a.x * b.y - a.y * b.x};
}
__device__ __forceinline__ F3 ldp(const float* p) { return {p[0], p[1], p[2]}; }

// ---------------- nonbonded all-pairs (gather, tiled) ----------------
// pairs are all (i,j), |i-j| >= 3 (1-2 and 1-3 excluded by construction).
// F_i += s * (p_j - p_i),  s = -C/d^3 + (6*B*sr6 - 12*A*sr12)/d^2
__global__ __launch_bounds__(256) void nb_kernel(
    const float* __restrict__ pos, const float* __restrict__ bead_radii,
    const float* __restrict__ q_vals, const float* __restrict__ disp_k,
    const float* __restrict__ hbond_k, const float* __restrict__ e_r,
    const float* __restrict__ f_0, const int* __restrict__ bead_types,
    const int* __restrict__ charge_idx, const int* __restrict__ nb_tid,
    float* __restrict__ out, int N, int n_nbt, int jsplit)
{
    __shared__ float4 sj[128];   // x,y,z,q of j-tile
    __shared__ float  srad[128];
    __shared__ int    sbase[128]; // pair-index row base for j (fallback path)
    __shared__ int    sflag;

    const int tid = threadIdx.x;
    const int b = blockIdx.y;
    const int itile = blockIdx.x / jsplit;
    const int jc = blockIdx.x - itile * jsplit;
    const int i = itile * 256 + tid;
    const int j0 = jc * 128;

    if (tid == 0) sflag = 1;
    __syncthreads();

    const float A0 = disp_k[0], B0 = hbond_k[0];
    for (int t = tid; t < n_nbt; t += 256)
        if (disp_k[t] != A0 || hbond_k[t] != B0) sflag = 0;

    if (tid < 128) {
        int j = j0 + tid;
        const float* pj = pos + ((size_t)b * N + j) * 3;
        float qj = q_vals[charge_idx[j]];
        sj[tid] = make_float4(pj[0], pj[1], pj[2], qj);
        srad[tid] = bead_radii[bead_types[j]];
        sbase[tid] = j * (N - 3) - (j * (j - 1)) / 2;
    }

    const float* pi = pos + ((size_t)b * N + i) * 3;
    const float pix = pi[0], piy = pi[1], piz = pi[2];
    const float qi = q_vals[charge_idx[i]];
    const float radi = bead_radii[bead_types[i]];
    const float f0e = f_0[0] / e_r[0];
    const int basei = i * (N - 3) - (i * (i - 1)) / 2;
    const int ji = j0 - i;

    __syncthreads();
    const bool uni = (sflag != 0);

    float fx = 0.f, fy = 0.f, fz = 0.f;
    float A = A0, Bc = B0;
#pragma unroll 4
    for (int jj = 0; jj < 128; ++jj) {
        float4 pj = sj[jj];
        float rx = pj.x - pix, ry = pj.y - piy, rz = pj.z - piz;
        int dj = ji + jj; // j - i
        if (dj > 2 || dj < -2) {
            if (!uni) { // fallback: per-pair type lookup
                int pidx = (dj > 0) ? (basei + dj - 3) : (sbase[jj] - dj - 3);
                int tt = nb_tid[pidx];
                A = disp_k[tt];
                Bc = hbond_k[tt];
            }
            float d2 = fmaf(rx, rx, fmaf(ry, ry, fmaf(rz, rz, EPSF)));
            float inv = rsqrtf(d2);
            inv = inv * fmaf(-0.5f * d2 * inv, inv, 1.5f); // NR refine
            float inv2 = inv * inv;
            float C = f0e * qi * pj.w;
            float sig = radi + srad[jj];
            float sr2 = sig * sig * inv2;
            float sr6 = sr2 * sr2 * sr2;
            float s = fmaf(6.f * Bc, sr6, -12.f * A * sr6 * sr6);
            s = s * inv2 - C * inv2 * inv;
            fx = fmaf(s, rx, fx);
            fy = fmaf(s, ry, fy);
            fz = fmaf(s, rz, fz);
        }
    }
    size_t o = ((size_t)b * N + i) * 3;
    atomicAdd(&out[o + 0], fx);
    atomicAdd(&out[o + 1], fy);
    atomicAdd(&out[o + 2], fz);
}

// ---------------- bonded terms (bond + angle + dihedral), atomic scatter ----------------
__global__ __launch_bounds__(256) void bonded_kernel(
    const float* __restrict__ pos,
    const float* __restrict__ spring_k, const float* __restrict__ bond_d0,
    const float* __restrict__ angle_k, const float* __restrict__ angle_th0,
    const float* __restrict__ dih_k, const float* __restrict__ dih_phi0,
    const int* __restrict__ bond_idx, const int* __restrict__ bond_tid,
    const int* __restrict__ angle_idx, const int* __restrict__ angle_tid,
    const int* __restrict__ dih_idx, const int* __restrict__ dih_tid,
    float* __restrict__ out, int B, int N, int nbond, int nang, int ndih)
{
    int t = blockIdx.x * blockDim.x + threadIdx.x;
    const int nb_tot = B * nbond;
    const int na_tot = B * nang;
    const int nd_tot = B * ndih;

    if (t < nb_tot) {
        // ---- bonds: E = 0.5*k*(d-d0)^2, rb = pa - pb
        int b = t / nbond, e = t - b * nbond;
        int ia = bond_idx[2 * e], ib = bond_idx[2 * e + 1];
        const float* pa = pos + ((size_t)b * N + ia) * 3;
        const float* pb = pos + ((size_t)b * N + ib) * 3;
        float rx = pa[0] - pb[0], ry = pa[1] - pb[1], rz = pa[2] - pb[2];
        float d = sqrtf(rx * rx + ry * ry + rz * rz + EPSF);
        int ty = bond_tid[e];
        float coef = -spring_k[ty] * (d - bond_d0[ty]) / d; // F_a = coef*r, F_b = -coef*r
        size_t oa = ((size_t)b * N + ia) * 3, ob = ((size_t)b * N + ib) * 3;
        atomicAdd(&out[oa + 0], coef * rx);
        atomicAdd(&out[oa + 1], coef * ry);
        atomicAdd(&out[oa + 2], coef * rz);
        atomicAdd(&out[ob + 0], -coef * rx);
        atomicAdd(&out[ob + 1], -coef * ry);
        atomicAdd(&out[ob + 2], -coef * rz);
    } else if (t < nb_tot + na_tot) {
        // ---- angles: theta = acos(clip(u.v / sqrt(uu*vv+EPS)))
        int tt = t - nb_tot;
        int b = tt / nang, e = tt - b * nang;
        int i0 = angle_idx[3 * e], i1 = angle_idx[3 * e + 1], i2 = angle_idx[3 * e + 2];
        F3 p0 = ldp(pos + ((size_t)b * N + i0) * 3);
        F3 p1 = ldp(pos + ((size_t)b * N + i1) * 3);
        F3 p2 = ldp(pos + ((size_t)b * N + i2) * 3);
        F3 u = p0 - p1, v = p2 - p1;
        float uu = dot3(u, u), vv = dot3(v, v), uv = dot3(u, v);
        float den = sqrtf(uu * vv + EPSF);
        float c = uv / den;
        const float lo = -1.f + 1e-6f, hi = 1.f - 1e-6f;
        float cl = fminf(fmaxf(c, lo), hi);
        float theta = acosf(cl);
        int ty = angle_tid[e];
        bool inr = (c > lo) && (c < hi);
        // g = dE/dc = k*(theta-th0) * d(theta)/d(cl) * [clip passthrough]
        float g = inr ? (-angle_k[ty] * (theta - angle_th0[ty]) * rsqrtf(1.f - cl * cl)) : 0.f;
        float invden = 1.f / den;
        float invden3 = invden * invden * invden;
        F3 dcdu = invden * v - (uv * vv * invden3) * u;
        F3 dcdv = invden * u - (uv * uu * invden3) * v;
        F3 F0 = (-g) * dcdu;        // F = -dE/dp
        F3 F2 = (-g) * dcdv;
        F3 F1 = mkf3(-(F0.x + F2.x), -(F0.y + F2.y), -(F0.z + F2.z));
        size_t o0 = ((size_t)b * N + i0) * 3, o1 = ((size_t)b * N + i1) * 3, o2 = ((size_t)b * N + i2) * 3;
        atomicAdd(&out[o0 + 0], F0.x); atomicAdd(&out[o0 + 1], F0.y); atomicAdd(&out[o0 + 2], F0.z);
        atomicAdd(&out[o1 + 0], F1.x); atomicAdd(&out[o1 + 1], F1.y); atomicAdd(&out[o1 + 2], F1.z);
        atomicAdd(&out[o2 + 0], F2.x); atomicAdd(&out[o2 + 1], F2.y); atomicAdd(&out[o2 + 2], F2.z);
    } else if (t < nb_tot + na_tot + nd_tot) {
        // ---- dihedrals: phi = atan2(m1.n2, n1.n2)
        int tt = t - nb_tot - na_tot;
        int b = tt / ndih, e = tt - b * ndih;
        int i0 = dih_idx[4 * e], i1 = dih_idx[4 * e + 1], i2 = dih_idx[4 * e + 2], i3 = dih_idx[4 * e + 3];
        F3 p0 = ldp(pos + ((size_t)b * N + i0) * 3);
        F3 p1 = ldp(pos + ((size_t)b * N + i1) * 3);
        F3 p2 = ldp(pos + ((size_t)b * N + i2) * 3);
        F3 p3 = ldp(pos + ((size_t)b * N + i3) * 3);
        F3 b1 = p1 - p0, b2 = p2 - p1, b3 = p3 - p2;
        F3 n1 = cross3(b1, b2), n2 = cross3(b2, b3);
        float L2 = dot3(b2, b2) + EPSF;
        float L = sqrtf(L2);
        F3 b2u = (1.f / L) * b2;
        F3 m1 = cross3(n1, b2u);
        float x = dot3(n1, n2), y = dot3(m1, n2);
        float phi = atan2f(y, x);
        int ty = dih_tid[e];
        float dEdphi = dih_k[ty] * (phi - dih_phi0[ty]);
        float inv_xy = 1.f / (x * x + y * y);

        // d(x)/db*, d(y)/db* (triple-product derivatives)
        F3 gx_b1 = cross3(b2, n2);
        F3 gx_b2 = cross3(n2, b1) + cross3(b3, n1);
        F3 gx_b3 = cross3(n1, b2);
        F3 bun2 = cross3(b2u, n2);
        F3 gy_b1 = cross3(b2, bun2);
        F3 w = cross3(n2, n1);
        F3 gy_b2 = cross3(bun2, b1) + cross3(b3, m1) + (1.f / L) * (w - (dot3(b2, w) / L2) * b2);
        F3 gy_b3 = cross3(m1, b2);

        // dphi/db = (x*gy - y*gx) * inv_xy ;  dE/db = dEdphi * dphi/db
        float cx = dEdphi * inv_xy;
        F3 dE_b1 = cx * (x * gy_b1 - y * gx_b1 + mkf3(0, 0, 0));
        F3 dE_b2 = cx * (x * gy_b2 - y * gx_b2 + mkf3(0, 0, 0));
        F3 dE_b3 = cx * (x * gy_b3 - y * gx_b3 + mkf3(0, 0, 0));
        // F = -dE/dp:  dE/dp0=-dE_b1, dE/dp1=dE_b1-dE_b2, dE/dp2=dE_b2-dE_b3, dE/dp3=dE_b3
        F3 F0 = dE_b1;
        F3 F1 = dE_b2 - dE_b1;
        F3 F2 = dE_b3 - dE_b2;
        F3 F3v = mkf3(-dE_b3.x, -dE_b3.y, -dE_b3.z);
        size_t o0 = ((size_t)b * N + i0) * 3, o1 = ((size_t)b * N + i1) * 3;
        size_t o2 = ((size_t)b * N + i2) * 3, o3 = ((size_t)b * N + i3) * 3;
        atomicAdd(&out[o0 + 0], F0.x); atomicAdd(&out[o0 + 1], F0.y); atomicAdd(&out[o0 + 2], F0.z);
        atomicAdd(&out[o1 + 0], F1.x); atomicAdd(&out[o1 + 1], F1.y); atomicAdd(&out[o1 + 2], F1.z);
        atomicAdd(&out[o2 + 0], F2.x); atomicAdd(&out[o2 + 1], F2.y); atomicAdd(&out[o2 + 2], F2.z);
        atomicAdd(&out[o3 + 0], F3v.x); atomicAdd(&out[o3 + 1], F3v.y); atomicAdd(&out[o3 + 2], F3v.z);
    }
}

extern "C" void kernel_launch(void* const* d_in, const int* in_sizes, int n_in,
                              void* d_out, int out_size, void* d_ws, size_t ws_size,
                              hipStream_t stream) {
    const float* pos = (const float*)d_in[0];
    const float* bead_radii = (const float*)d_in[1];
    const float* q_vals = (const float*)d_in[2];
    const float* spring_k = (const float*)d_in[3];
    const float* bond_d0 = (const float*)d_in[4];
    const float* angle_k = (const float*)d_in[5];
    const float* angle_th0 = (const float*)d_in[6];
    const float* dih_k = (const float*)d_in[7];
    const float* dih_phi0 = (const float*)d_in[8];
    const float* disp_k = (const float*)d_in[9];
    const float* hbond_k = (const float*)d_in[10];
    const float* e_r = (const float*)d_in[11];
    const float* f_0 = (const float*)d_in[12];
    const int* bead_types = (const int*)d_in[13];
    const int* charge_idx = (const int*)d_in[14];
    const int* bond_idx = (const int*)d_in[15];
    const int* bond_tid = (const int*)d_in[16];
    const int* angle_idx = (const int*)d_in[17];
    const int* angle_tid = (const int*)d_in[18];
    const int* dih_idx = (const int*)d_in[19];
    const int* dih_tid = (const int*)d_in[20];
    const int* nb_tid = (const int*)d_in[23];
    float* out = (float*)d_out;

    const int N = in_sizes[13];             // 2048
    const int B = in_sizes[0] / (N * 3);    // 4
    const int nbond = in_sizes[16];         // N-1
    const int nang = in_sizes[18];          // N-2
    const int ndih = in_sizes[20];          // 512
    const int n_nbt = in_sizes[9];          // 256

    hipMemsetAsync(d_out, 0, (size_t)out_size * sizeof(float), stream);

    const int jsplit = N / 128;             // 16
    dim3 g1((N / 256) * jsplit, B);         // (128, 4)
    nb_kernel<<<g1, 256, 0, stream>>>(pos, bead_radii, q_vals, disp_k, hbond_k, e_r, f_0,
                                      bead_types, charge_idx, nb_tid, out, N, n_nbt, jsplit);

    int tot = B * (nbond + nang + ndih);
    bonded_kernel<<<(tot + 255) / 256, 256, 0, stream>>>(
        pos, spring_k, bond_d0, angle_k, angle_th0, dih_k, dih_phi0,
        bond_idx, bond_tid, angle_idx, angle_tid, dih_idx, dih_tid,
        out, B, N, nbond, nang, ndih);
}

// Round 2
// 29.308 us; speedup vs baseline: 1.2752x; 1.2752x over previous
//
#include <hip/hip_runtime.h>
#include <math.h>

#define EPSF 1e-12f

// ---------------- small float3 helpers ----------------
struct F3 { float x, y, z; };
__device__ __forceinline__ F3 mkf3(float a, float b, float c) { return {a, b, c}; }
__device__ __forceinline__ F3 operator-(F3 a, F3 b) { return {a.x - b.x, a.y - b.y, a.z - b.z}; }
__device__ __forceinline__ F3 operator+(F3 a, F3 b) { return {a.x + b.x, a.y + b.y, a.z + b.z}; }
__device__ __forceinline__ F3 operator-(F3 a) { return {-a.x, -a.y, -a.z}; }
__device__ __forceinline__ F3 operator*(float s, F3 a) { return {s * a.x, s * a.y, s * a.z}; }
__device__ __forceinline__ float dot3(F3 a, F3 b) { return a.x * b.x + a.y * b.y + a.z * b.z; }
__device__ __forceinline__ F3 cross3(F3 a, F3 b) {
    return {a.y * b.z - a.z * b.y, a.z * b.x - a.x * b.z, a.x * b.y - a.y * b.x};
}
__device__ __forceinline__ F3 ldp(const float* p) { return {p[0], p[1], p[2]}; }

// ---------------- nonbonded all-pairs (gather, tiled, no atomics) ----------------
// pairs: all (i,j), |i-j| >= 3.  F_i += s*(p_j - p_i),
// s = inv2*(lj - C*inv),  lj = 6*B*sr6 - 12*A*sr12,  C = f0/e_r * qi*qj
__global__ __launch_bounds__(256) void nb_kernel(
    const float* __restrict__ pos, const float* __restrict__ bead_radii,
    const float* __restrict__ q_vals, const float* __restrict__ disp_k,
    const float* __restrict__ hbond_k, const float* __restrict__ e_r,
    const float* __restrict__ f_0, const int* __restrict__ bead_types,
    const int* __restrict__ charge_idx, const int* __restrict__ nb_tid,
    float* __restrict__ ws, int N, int n_nbt, int n_bt, int jsplit)
{
    __shared__ float4 sj[128];   // x,y,z,q of j-tile
    __shared__ float  srad[128];
    __shared__ int    sbase[128];
    __shared__ int    sflag;

    const int tid = threadIdx.x;
    const int b = blockIdx.y;
    const int itile = blockIdx.x / jsplit;
    const int jc = blockIdx.x - itile * jsplit;
    const int i = itile * 256 + tid;
    const int j0 = jc * 128;

    if (tid == 0) sflag = 1;
    __syncthreads();

    const float A0 = disp_k[0], B0 = hbond_k[0], R0 = bead_radii[0];
    for (int t = tid; t < n_nbt; t += 256)
        if (disp_k[t] != A0 || hbond_k[t] != B0) sflag = 0;
    if (tid < n_bt && bead_radii[tid] != R0) sflag = 0;

    if (tid < 128) {
        int j = j0 + tid;
        const float* pj = pos + ((size_t)b * N + j) * 3;
        sj[tid] = make_float4(pj[0], pj[1], pj[2], q_vals[charge_idx[j]]);
        srad[tid] = bead_radii[bead_types[j]];
        sbase[tid] = j * (N - 3) - (j * (j - 1)) / 2;
    }

    const float* pi = pos + ((size_t)b * N + i) * 3;
    const float pix = pi[0], piy = pi[1], piz = pi[2];
    const float f0e = f_0[0] / e_r[0];
    const float qis = f0e * q_vals[charge_idx[i]];
    const float radi = bead_radii[bead_types[i]];

    __syncthreads();
    const bool uni = (sflag != 0);

    float fx = 0.f, fy = 0.f, fz = 0.f;

    if (uni) {
        const float sig2 = 4.f * R0 * R0;      // (2*R0)^2
        const float c6 = 6.f * B0, c12n = -12.f * A0;
        const int iLo = itile * 256, iHi = iLo + 255;
        const bool far = (j0 > iHi + 2) || (j0 + 127 < iLo - 2);
        if (far) {
#pragma unroll 8
            for (int jj = 0; jj < 128; ++jj) {
                float4 pj = sj[jj];
                float rx = pj.x - pix, ry = pj.y - piy, rz = pj.z - piz;
                float d2 = fmaf(rx, rx, fmaf(ry, ry, fmaf(rz, rz, EPSF)));
                float inv = rsqrtf(d2);
                float inv2 = inv * inv;
                float sr2 = sig2 * inv2;
                float sr6 = sr2 * sr2 * sr2;
                float lj = sr6 * fmaf(c12n, sr6, c6);
                float s = inv2 * fmaf(-qis * pj.w, inv, lj);
                fx = fmaf(s, rx, fx); fy = fmaf(s, ry, fy); fz = fmaf(s, rz, fz);
            }
        } else {
#pragma unroll 4
            for (int jj = 0; jj < 128; ++jj) {
                float4 pj = sj[jj];
                float rx = pj.x - pix, ry = pj.y - piy, rz = pj.z - piz;
                int dj = j0 + jj - i;
                float d2 = fmaf(rx, rx, fmaf(ry, ry, fmaf(rz, rz, EPSF)));
                float inv = rsqrtf(d2);
                float inv2 = inv * inv;
                float sr2 = sig2 * inv2;
                float sr6 = sr2 * sr2 * sr2;
                float lj = sr6 * fmaf(c12n, sr6, c6);
                float s = inv2 * fmaf(-qis * pj.w, inv, lj);
                bool val = (dj > 2) || (dj < -2);
                s = val ? s : 0.f;
                fx = fmaf(s, rx, fx); fy = fmaf(s, ry, fy); fz = fmaf(s, rz, fz);
            }
        }
    } else {
        // generic fallback: per-pair type lookup (analytic pair index)
        const int basei = i * (N - 3) - (i * (i - 1)) / 2;
        const int ji = j0 - i;
        for (int jj = 0; jj < 128; ++jj) {
            float4 pj = sj[jj];
            float rx = pj.x - pix, ry = pj.y - piy, rz = pj.z - piz;
            int dj = ji + jj;
            if (dj > 2 || dj < -2) {
                int pidx = (dj > 0) ? (basei + dj - 3) : (sbase[jj] - dj - 3);
                int tt = nb_tid[pidx];
                float A = disp_k[tt], Bc = hbond_k[tt];
                float d2 = fmaf(rx, rx, fmaf(ry, ry, fmaf(rz, rz, EPSF)));
                float inv = rsqrtf(d2);
                inv = inv * fmaf(-0.5f * d2 * inv, inv, 1.5f);
                float inv2 = inv * inv;
                float sig = radi + srad[jj];
                float sr2 = sig * sig * inv2;
                float sr6 = sr2 * sr2 * sr2;
                float lj = sr6 * fmaf(-12.f * A, sr6, 6.f * Bc);
                float s = inv2 * fmaf(-qis * pj.w, inv, lj);
                fx = fmaf(s, rx, fx); fy = fmaf(s, ry, fy); fz = fmaf(s, rz, fz);
            }
        }
    }

    // store partials, SoA for coalescing: ws[(blk*3+c)*N + i]
    const size_t blk = (size_t)b * jsplit + jc;
    ws[(blk * 3 + 0) * N + i] = fx;
    ws[(blk * 3 + 1) * N + i] = fy;
    ws[(blk * 3 + 2) * N + i] = fz;
}

// ---------------- bonded force contributions (gather form) ----------------
__device__ __forceinline__ F3 bond_force(const float* posb, int k, int side,
    const float* __restrict__ spring_k, const float* __restrict__ bond_d0,
    const int* __restrict__ bond_tid)
{
    F3 pa = ldp(posb + (size_t)k * 3);
    F3 pb = ldp(posb + (size_t)(k + 1) * 3);
    F3 r = pa - pb;
    float d = sqrtf(dot3(r, r) + EPSF);
    int ty = bond_tid[k];
    float coef = -spring_k[ty] * (d - bond_d0[ty]) / d;
    return (side == 0 ? coef : -coef) * r;
}

__device__ __forceinline__ F3 angle_force(const float* posb, int k, int p,
    const float* __restrict__ angle_k_arr, const float* __restrict__ angle_th0,
    const int* __restrict__ angle_tid)
{
    F3 p0 = ldp(posb + (size_t)k * 3);
    F3 p1 = ldp(posb + (size_t)(k + 1) * 3);
    F3 p2 = ldp(posb + (size_t)(k + 2) * 3);
    F3 u = p0 - p1, v = p2 - p1;
    float uu = dot3(u, u), vv = dot3(v, v), uv = dot3(u, v);
    float den = sqrtf(uu * vv + EPSF);
    float c = uv / den;
    const float lo = -1.f + 1e-6f, hi = 1.f - 1e-6f;
    float cl = fminf(fmaxf(c, lo), hi);
    float theta = acosf(cl);
    int ty = angle_tid[k];
    bool inr = (c > lo) && (c < hi);
    float g = inr ? (-angle_k_arr[ty] * (theta - angle_th0[ty]) * rsqrtf(1.f - cl * cl)) : 0.f;
    float invden = 1.f / den;
    float invden3 = invden * invden * invden;
    F3 dcdu = invden * v - (uv * vv * invden3) * u;
    F3 dcdv = invden * u - (uv * uu * invden3) * v;
    F3 F0 = (-g) * dcdu;
    F3 F2 = (-g) * dcdv;
    if (p == 0) return F0;
    if (p == 2) return F2;
    return mkf3(-(F0.x + F2.x), -(F0.y + F2.y), -(F0.z + F2.z));
}

__device__ __forceinline__ F3 dih_force(const float* posb, int k, int p,
    const float* __restrict__ dih_k_arr, const float* __restrict__ dih_phi0,
    const int* __restrict__ dih_tid)
{
    F3 p0 = ldp(posb + (size_t)k * 3);
    F3 p1 = ldp(posb + (size_t)(k + 1) * 3);
    F3 p2 = ldp(posb + (size_t)(k + 2) * 3);
    F3 p3 = ldp(posb + (size_t)(k + 3) * 3);
    F3 b1 = p1 - p0, b2 = p2 - p1, b3 = p3 - p2;
    F3 n1 = cross3(b1, b2), n2 = cross3(b2, b3);
    float L2 = dot3(b2, b2) + EPSF;
    float L = sqrtf(L2);
    F3 b2u = (1.f / L) * b2;
    F3 m1 = cross3(n1, b2u);
    float x = dot3(n1, n2), y = dot3(m1, n2);
    float phi = atan2f(y, x);
    int ty = dih_tid[k];
    float dEdphi = dih_k_arr[ty] * (phi - dih_phi0[ty]);
    float inv_xy = 1.f / (x * x + y * y);

    F3 gx_b1 = cross3(b2, n2);
    F3 gx_b2 = cross3(n2, b1) + cross3(b3, n1);
    F3 gx_b3 = cross3(n1, b2);
    F3 bun2 = cross3(b2u, n2);
    F3 gy_b1 = cross3(b2, bun2);
    F3 w = cross3(n2, n1);
    F3 gy_b2 = cross3(bun2, b1) + cross3(b3, m1) + (1.f / L) * (w - (dot3(b2, w) / L2) * b2);
    F3 gy_b3 = cross3(m1, b2);

    float cx = dEdphi * inv_xy;
    F3 dE_b1 = cx * (x * gy_b1 - y * gx_b1);
    F3 dE_b2 = cx * (x * gy_b2 - y * gx_b2);
    F3 dE_b3 = cx * (x * gy_b3 - y * gx_b3);
    if (p == 0) return dE_b1;
    if (p == 1) return dE_b2 - dE_b1;
    if (p == 2) return dE_b3 - dE_b2;
    return -dE_b3;
}

// ---------------- reduce partials + bonded gather, single plain store ----------------
__global__ __launch_bounds__(64) void finish_kernel(
    const float* __restrict__ pos, const float* __restrict__ ws,
    const float* __restrict__ spring_k, const float* __restrict__ bond_d0,
    const float* __restrict__ angle_k, const float* __restrict__ angle_th0,
    const float* __restrict__ dih_k, const float* __restrict__ dih_phi0,
    const int* __restrict__ bond_tid, const int* __restrict__ angle_tid,
    const int* __restrict__ dih_tid,
    float* __restrict__ out, int B, int N, int nbond, int nang, int ndih, int jsplit)
{
    int t = blockIdx.x * 64 + threadIdx.x;
    if (t >= B * N) return;
    int b = t / N, i = t - b * N;

    float fx = 0.f, fy = 0.f, fz = 0.f;
    for (int jc = 0; jc < jsplit; ++jc) {
        size_t blk = (size_t)b * jsplit + jc;
        fx += ws[(blk * 3 + 0) * N + i];
        fy += ws[(blk * 3 + 1) * N + i];
        fz += ws[(blk * 3 + 2) * N + i];
    }

    const float* posb = pos + (size_t)b * N * 3;
    F3 F = mkf3(fx, fy, fz);

    // bonds: k=(k,k+1); atom i is first in bond i, second in bond i-1
    if (i <= nbond - 1) F = F + bond_force(posb, i, 0, spring_k, bond_d0, bond_tid);
    if (i >= 1)         F = F + bond_force(posb, i - 1, 1, spring_k, bond_d0, bond_tid);

    // angles: k=(k,k+1,k+2); atom i plays role p in angle k=i-p
#pragma unroll
    for (int p = 0; p < 3; ++p) {
        int k = i - p;
        if (k >= 0 && k <= nang - 1)
            F = F + angle_force(posb, k, p, angle_k, angle_th0, angle_tid);
    }

    // dihedrals: k=(k..k+3); atom i plays role p in dih k=i-p
#pragma unroll
    for (int p = 0; p < 4; ++p) {
        int k = i - p;
        if (k >= 0 && k < ndih)
            F = F + dih_force(posb, k, p, dih_k, dih_phi0, dih_tid);
    }

    size_t o = ((size_t)b * N + i) * 3;
    out[o + 0] = F.x;
    out[o + 1] = F.y;
    out[o + 2] = F.z;
}

extern "C" void kernel_launch(void* const* d_in, const int* in_sizes, int n_in,
                              void* d_out, int out_size, void* d_ws, size_t ws_size,
                              hipStream_t stream) {
    const float* pos = (const float*)d_in[0];
    const float* bead_radii = (const float*)d_in[1];
    const float* q_vals = (const float*)d_in[2];
    const float* spring_k = (const float*)d_in[3];
    const float* bond_d0 = (const float*)d_in[4];
    const float* angle_k = (const float*)d_in[5];
    const float* angle_th0 = (const float*)d_in[6];
    const float* dih_k = (const float*)d_in[7];
    const float* dih_phi0 = (const float*)d_in[8];
    const float* disp_k = (const float*)d_in[9];
    const float* hbond_k = (const float*)d_in[10];
    const float* e_r = (const float*)d_in[11];
    const float* f_0 = (const float*)d_in[12];
    const int* bead_types = (const int*)d_in[13];
    const int* charge_idx = (const int*)d_in[14];
    const int* bond_tid = (const int*)d_in[16];
    const int* angle_tid = (const int*)d_in[18];
    const int* dih_tid = (const int*)d_in[20];
    const int* nb_tid = (const int*)d_in[23];
    float* out = (float*)d_out;
    float* ws = (float*)d_ws;

    const int N = in_sizes[13];             // 2048
    const int B = in_sizes[0] / (N * 3);    // 4
    const int nbond = in_sizes[16];         // N-1
    const int nang = in_sizes[18];          // N-2
    const int ndih = in_sizes[20];          // 512
    const int n_nbt = in_sizes[9];          // 256
    const int n_bt = in_sizes[1];           // 16

    const int jsplit = N / 128;             // 16
    dim3 g1((N / 256) * jsplit, B);         // (128, 4) = 512 blocks
    nb_kernel<<<g1, 256, 0, stream>>>(pos, bead_radii, q_vals, disp_k, hbond_k, e_r, f_0,
                                      bead_types, charge_idx, nb_tid, ws, N, n_nbt, n_bt, jsplit);

    int tot = B * N;
    finish_kernel<<<(tot + 63) / 64, 64, 0, stream>>>(
        pos, ws, spring_k, bond_d0, angle_k, angle_th0, dih_k, dih_phi0,
        bond_tid, angle_tid, dih_tid, out, B, N, nbond, nang, ndih, jsplit);
}

// Round 3
// 28.062 us; speedup vs baseline: 1.3319x; 1.0444x over previous
//
#include <hip/hip_runtime.h>
#include <math.h>

#define EPSF 1e-12f
#define TJ 64           // j-tile size
#define JS 32           // jsplit = N / TJ (runtime-checked)

// ---------------- small float3 helpers ----------------
struct F3 { float x, y, z; };
__device__ __forceinline__ F3 mkf3(float a, float b, float c) { return {a, b, c}; }
__device__ __forceinline__ F3 operator-(F3 a, F3 b) { return {a.x - b.x, a.y - b.y, a.z - b.z}; }
__device__ __forceinline__ F3 operator+(F3 a, F3 b) { return {a.x + b.x, a.y + b.y, a.z + b.z}; }
__device__ __forceinline__ F3 operator-(F3 a) { return {-a.x, -a.y, -a.z}; }
__device__ __forceinline__ F3 operator*(float s, F3 a) { return {s * a.x, s * a.y, s * a.z}; }
__device__ __forceinline__ float dot3(F3 a, F3 b) { return a.x * b.x + a.y * b.y + a.z * b.z; }
__device__ __forceinline__ F3 cross3(F3 a, F3 b) {
    return {a.y * b.z - a.z * b.y, a.z * b.x - a.x * b.z, a.x * b.y - a.y * b.x};
}
__device__ __forceinline__ F3 ldp(const float* p) { return {p[0], p[1], p[2]}; }

// ---------------- nonbonded all-pairs (gather, tiled, no atomics) ----------------
__global__ __launch_bounds__(256) void nb_kernel(
    const float* __restrict__ pos, const float* __restrict__ bead_radii,
    const float* __restrict__ q_vals, const float* __restrict__ disp_k,
    const float* __restrict__ hbond_k, const float* __restrict__ e_r,
    const float* __restrict__ f_0, const int* __restrict__ bead_types,
    const int* __restrict__ charge_idx, const int* __restrict__ nb_tid,
    float* __restrict__ ws, int N, int n_nbt, int n_bt, int jsplit)
{
    __shared__ float4 sj[TJ];   // x,y,z,q of j-tile
    __shared__ float  srad[TJ];
    __shared__ int    sbase[TJ];
    __shared__ int    sflag;

    const int tid = threadIdx.x;
    const int b = blockIdx.y;
    const int itile = blockIdx.x / jsplit;
    const int jc = blockIdx.x - itile * jsplit;
    const int i = itile * 256 + tid;
    const int j0 = jc * TJ;

    if (tid == 0) sflag = 1;
    __syncthreads();

    const float A0 = disp_k[0], B0 = hbond_k[0], R0 = bead_radii[0];
    for (int t = tid; t < n_nbt; t += 256)
        if (disp_k[t] != A0 || hbond_k[t] != B0) sflag = 0;
    if (tid < n_bt && bead_radii[tid] != R0) sflag = 0;

    if (tid < TJ) {
        int j = j0 + tid;
        const float* pj = pos + ((size_t)b * N + j) * 3;
        sj[tid] = make_float4(pj[0], pj[1], pj[2], q_vals[charge_idx[j]]);
        srad[tid] = bead_radii[bead_types[j]];
        sbase[tid] = j * (N - 3) - (j * (j - 1)) / 2;
    }

    const float* pi = pos + ((size_t)b * N + i) * 3;
    const float pix = pi[0], piy = pi[1], piz = pi[2];
    const float f0e = f_0[0] / e_r[0];
    const float qis = f0e * q_vals[charge_idx[i]];
    const float radi = bead_radii[bead_types[i]];

    __syncthreads();
    const bool uni = (sflag != 0);

    float fx = 0.f, fy = 0.f, fz = 0.f;

    if (uni) {
        const float sig2 = 4.f * R0 * R0;
        const float c6 = 6.f * B0, c12n = -12.f * A0;
        const int iLo = itile * 256, iHi = iLo + 255;
        const bool far = (j0 > iHi + 2) || (j0 + TJ - 1 < iLo - 2);
        if (far) {
#pragma unroll 8
            for (int jj = 0; jj < TJ; ++jj) {
                float4 pj = sj[jj];
                float rx = pj.x - pix, ry = pj.y - piy, rz = pj.z - piz;
                float d2 = fmaf(rx, rx, fmaf(ry, ry, fmaf(rz, rz, EPSF)));
                float inv = __builtin_amdgcn_rsqf(d2);
                float inv2 = inv * inv;
                float sr2 = sig2 * inv2;
                float sr6 = sr2 * sr2 * sr2;
                float lj = sr6 * fmaf(c12n, sr6, c6);
                float s = inv2 * fmaf(-qis * pj.w, inv, lj);
                fx = fmaf(s, rx, fx); fy = fmaf(s, ry, fy); fz = fmaf(s, rz, fz);
            }
        } else {
#pragma unroll 4
            for (int jj = 0; jj < TJ; ++jj) {
                float4 pj = sj[jj];
                float rx = pj.x - pix, ry = pj.y - piy, rz = pj.z - piz;
                int dj = j0 + jj - i;
                float d2 = fmaf(rx, rx, fmaf(ry, ry, fmaf(rz, rz, EPSF)));
                float inv = __builtin_amdgcn_rsqf(d2);
                float inv2 = inv * inv;
                float sr2 = sig2 * inv2;
                float sr6 = sr2 * sr2 * sr2;
                float lj = sr6 * fmaf(c12n, sr6, c6);
                float s = inv2 * fmaf(-qis * pj.w, inv, lj);
                bool val = (dj > 2) || (dj < -2);
                s = val ? s : 0.f;
                fx = fmaf(s, rx, fx); fy = fmaf(s, ry, fy); fz = fmaf(s, rz, fz);
            }
        }
    } else {
        // generic fallback: per-pair type lookup (analytic pair index)
        const int basei = i * (N - 3) - (i * (i - 1)) / 2;
        const int ji = j0 - i;
        for (int jj = 0; jj < TJ; ++jj) {
            float4 pj = sj[jj];
            float rx = pj.x - pix, ry = pj.y - piy, rz = pj.z - piz;
            int dj = ji + jj;
            if (dj > 2 || dj < -2) {
                int pidx = (dj > 0) ? (basei + dj - 3) : (sbase[jj] - dj - 3);
                int tt = nb_tid[pidx];
                float A = disp_k[tt], Bc = hbond_k[tt];
                float d2 = fmaf(rx, rx, fmaf(ry, ry, fmaf(rz, rz, EPSF)));
                float inv = rsqrtf(d2);
                inv = inv * fmaf(-0.5f * d2 * inv, inv, 1.5f);
                float inv2 = inv * inv;
                float sig = radi + srad[jj];
                float sr2 = sig * sig * inv2;
                float sr6 = sr2 * sr2 * sr2;
                float lj = sr6 * fmaf(-12.f * A, sr6, 6.f * Bc);
                float s = inv2 * fmaf(-qis * pj.w, inv, lj);
                fx = fmaf(s, rx, fx); fy = fmaf(s, ry, fy); fz = fmaf(s, rz, fz);
            }
        }
    }

    const size_t blk = (size_t)b * jsplit + jc;
    ws[(blk * 3 + 0) * N + i] = fx;
    ws[(blk * 3 + 1) * N + i] = fy;
    ws[(blk * 3 + 2) * N + i] = fz;
}

// ---------------- bonded force contributions (gather form) ----------------
__device__ __forceinline__ F3 bond_force(const float* posb, int k, int side,
    const float* __restrict__ spring_k, const float* __restrict__ bond_d0,
    const int* __restrict__ bond_tid)
{
    F3 pa = ldp(posb + (size_t)k * 3);
    F3 pb = ldp(posb + (size_t)(k + 1) * 3);
    F3 r = pa - pb;
    float d = sqrtf(dot3(r, r) + EPSF);
    int ty = bond_tid[k];
    float coef = -spring_k[ty] * (d - bond_d0[ty]) / d;
    return (side == 0 ? coef : -coef) * r;
}

__device__ __forceinline__ F3 angle_force(const float* posb, int k, int p,
    const float* __restrict__ angle_k_arr, const float* __restrict__ angle_th0,
    const int* __restrict__ angle_tid)
{
    F3 p0 = ldp(posb + (size_t)k * 3);
    F3 p1 = ldp(posb + (size_t)(k + 1) * 3);
    F3 p2 = ldp(posb + (size_t)(k + 2) * 3);
    F3 u = p0 - p1, v = p2 - p1;
    float uu = dot3(u, u), vv = dot3(v, v), uv = dot3(u, v);
    float den = sqrtf(uu * vv + EPSF);
    float c = uv / den;
    const float lo = -1.f + 1e-6f, hi = 1.f - 1e-6f;
    float cl = fminf(fmaxf(c, lo), hi);
    float theta = acosf(cl);
    int ty = angle_tid[k];
    bool inr = (c > lo) && (c < hi);
    float g = inr ? (-angle_k_arr[ty] * (theta - angle_th0[ty]) * rsqrtf(1.f - cl * cl)) : 0.f;
    float invden = 1.f / den;
    float invden3 = invden * invden * invden;
    F3 dcdu = invden * v - (uv * vv * invden3) * u;
    F3 dcdv = invden * u - (uv * uu * invden3) * v;
    F3 F0 = (-g) * dcdu;
    F3 F2 = (-g) * dcdv;
    if (p == 0) return F0;
    if (p == 2) return F2;
    return mkf3(-(F0.x + F2.x), -(F0.y + F2.y), -(F0.z + F2.z));
}

__device__ __forceinline__ F3 dih_force(const float* posb, int k, int p,
    const float* __restrict__ dih_k_arr, const float* __restrict__ dih_phi0,
    const int* __restrict__ dih_tid)
{
    F3 p0 = ldp(posb + (size_t)k * 3);
    F3 p1 = ldp(posb + (size_t)(k + 1) * 3);
    F3 p2 = ldp(posb + (size_t)(k + 2) * 3);
    F3 p3 = ldp(posb + (size_t)(k + 3) * 3);
    F3 b1 = p1 - p0, b2 = p2 - p1, b3 = p3 - p2;
    F3 n1 = cross3(b1, b2), n2 = cross3(b2, b3);
    float L2 = dot3(b2, b2) + EPSF;
    float L = sqrtf(L2);
    F3 b2u = (1.f / L) * b2;
    F3 m1 = cross3(n1, b2u);
    float x = dot3(n1, n2), y = dot3(m1, n2);
    float phi = atan2f(y, x);
    int ty = dih_tid[k];
    float dEdphi = dih_k_arr[ty] * (phi - dih_phi0[ty]);
    float inv_xy = 1.f / (x * x + y * y);

    F3 gx_b1 = cross3(b2, n2);
    F3 gx_b2 = cross3(n2, b1) + cross3(b3, n1);
    F3 gx_b3 = cross3(n1, b2);
    F3 bun2 = cross3(b2u, n2);
    F3 gy_b1 = cross3(b2, bun2);
    F3 w = cross3(n2, n1);
    F3 gy_b2 = cross3(bun2, b1) + cross3(b3, m1) + (1.f / L) * (w - (dot3(b2, w) / L2) * b2);
    F3 gy_b3 = cross3(m1, b2);

    float cx = dEdphi * inv_xy;
    F3 dE_b1 = cx * (x * gy_b1 - y * gx_b1);
    F3 dE_b2 = cx * (x * gy_b2 - y * gx_b2);
    F3 dE_b3 = cx * (x * gy_b3 - y * gx_b3);
    if (p == 0) return dE_b1;
    if (p == 1) return dE_b2 - dE_b1;
    if (p == 2) return dE_b3 - dE_b2;
    return -dE_b3;
}

// ---------------- finish: 8 lanes per atom, shfl reduce, plain store ----------------
__global__ __launch_bounds__(256) void finish_kernel(
    const float* __restrict__ pos, const float* __restrict__ ws,
    const float* __restrict__ spring_k, const float* __restrict__ bond_d0,
    const float* __restrict__ angle_k, const float* __restrict__ angle_th0,
    const float* __restrict__ dih_k, const float* __restrict__ dih_phi0,
    const int* __restrict__ bond_tid, const int* __restrict__ angle_tid,
    const int* __restrict__ dih_tid,
    float* __restrict__ out, int B, int N, int nbond, int nang, int ndih, int jsplit)
{
    int t = blockIdx.x * 256 + threadIdx.x;
    if (t >= B * N * 8) return;
    const int r = t & 7;
    const int ai = t >> 3;            // b*N + i
    const int b = ai / N, i = ai - b * N;
    const float* posb = pos + (size_t)b * N * 3;

    F3 F = mkf3(0.f, 0.f, 0.f);

    if (r < 4) {
        // each of lanes 0..3 sums jsplit/4 of the nb partials (all 3 comps)
        const int per = jsplit >> 2;
        const int jcs = r * per;
        for (int jc = jcs; jc < jcs + per; ++jc) {
            size_t blk = (size_t)b * jsplit + jc;
            F.x += ws[(blk * 3 + 0) * N + i];
            F.y += ws[(blk * 3 + 1) * N + i];
            F.z += ws[(blk * 3 + 2) * N + i];
        }
    } else if (r == 4) {
        if (i <= nbond - 1) F = F + bond_force(posb, i, 0, spring_k, bond_d0, bond_tid);
        if (i >= 1)         F = F + bond_force(posb, i - 1, 1, spring_k, bond_d0, bond_tid);
        if (i < ndih)       F = F + dih_force(posb, i, 0, dih_k, dih_phi0, dih_tid);
    } else if (r == 5) {
        if (i <= nang - 1)             F = F + angle_force(posb, i, 0, angle_k, angle_th0, angle_tid);
        if (i >= 1 && i - 1 <= nang - 1) F = F + angle_force(posb, i - 1, 1, angle_k, angle_th0, angle_tid);
    } else if (r == 6) {
        if (i >= 2 && i - 2 <= nang - 1) F = F + angle_force(posb, i - 2, 2, angle_k, angle_th0, angle_tid);
        if (i >= 1 && i - 1 < ndih)      F = F + dih_force(posb, i - 1, 1, dih_k, dih_phi0, dih_tid);
    } else {
        if (i >= 2 && i - 2 < ndih) F = F + dih_force(posb, i - 2, 2, dih_k, dih_phi0, dih_tid);
        if (i >= 3 && i - 3 < ndih) F = F + dih_force(posb, i - 3, 3, dih_k, dih_phi0, dih_tid);
    }

    // reduce across the 8 lanes of this atom
#pragma unroll
    for (int m = 1; m < 8; m <<= 1) {
        F.x += __shfl_xor(F.x, m, 64);
        F.y += __shfl_xor(F.y, m, 64);
        F.z += __shfl_xor(F.z, m, 64);
    }
    if (r == 0) {
        size_t o = (size_t)ai * 3;
        out[o + 0] = F.x;
        out[o + 1] = F.y;
        out[o + 2] = F.z;
    }
}

extern "C" void kernel_launch(void* const* d_in, const int* in_sizes, int n_in,
                              void* d_out, int out_size, void* d_ws, size_t ws_size,
                              hipStream_t stream) {
    const float* pos = (const float*)d_in[0];
    const float* bead_radii = (const float*)d_in[1];
    const float* q_vals = (const float*)d_in[2];
    const float* spring_k = (const float*)d_in[3];
    const float* bond_d0 = (const float*)d_in[4];
    const float* angle_k = (const float*)d_in[5];
    const float* angle_th0 = (const float*)d_in[6];
    const float* dih_k = (const float*)d_in[7];
    const float* dih_phi0 = (const float*)d_in[8];
    const float* disp_k = (const float*)d_in[9];
    const float* hbond_k = (const float*)d_in[10];
    const float* e_r = (const float*)d_in[11];
    const float* f_0 = (const float*)d_in[12];
    const int* bead_types = (const int*)d_in[13];
    const int* charge_idx = (const int*)d_in[14];
    const int* bond_tid = (const int*)d_in[16];
    const int* angle_tid = (const int*)d_in[18];
    const int* dih_tid = (const int*)d_in[20];
    const int* nb_tid = (const int*)d_in[23];
    float* out = (float*)d_out;
    float* ws = (float*)d_ws;

    const int N = in_sizes[13];             // 2048
    const int B = in_sizes[0] / (N * 3);    // 4
    const int nbond = in_sizes[16];         // N-1
    const int nang = in_sizes[18];          // N-2
    const int ndih = in_sizes[20];          // 512
    const int n_nbt = in_sizes[9];          // 256
    const int n_bt = in_sizes[1];           // 16

    const int jsplit = N / TJ;              // 32
    dim3 g1((N / 256) * jsplit, B);         // (256, 4) = 1024 blocks
    nb_kernel<<<g1, 256, 0, stream>>>(pos, bead_radii, q_vals, disp_k, hbond_k, e_r, f_0,
                                      bead_types, charge_idx, nb_tid, ws, N, n_nbt, n_bt, jsplit);

    int tot = B * N * 8;                    // 8 lanes per atom
    finish_kernel<<<(tot + 255) / 256, 256, 0, stream>>>(
        pos, ws, spring_k, bond_d0, angle_k, angle_th0, dih_k, dih_phi0,
        bond_tid, angle_tid, dih_tid, out, B, N, nbond, nang, ndih, jsplit);
}

// Round 4
// 20.236 us; speedup vs baseline: 1.8469x; 1.3867x over previous
//
#include <hip/hip_runtime.h>
#include <math.h>

#define EPSF 1e-12f
#define NMAX 2048
#define AT 32            // atoms per block
#define NT 256           // threads per block
#define SL 8             // j-slices per block (NT/AT)

// ---------------- small float3 helpers ----------------
struct F3 { float x, y, z; };
__device__ __forceinline__ F3 mkf3(float a, float b, float c) { return {a, b, c}; }
__device__ __forceinline__ F3 operator-(F3 a, F3 b) { return {a.x - b.x, a.y - b.y, a.z - b.z}; }
__device__ __forceinline__ F3 operator+(F3 a, F3 b) { return {a.x + b.x, a.y + b.y, a.z + b.z}; }
__device__ __forceinline__ F3 operator-(F3 a) { return {-a.x, -a.y, -a.z}; }
__device__ __forceinline__ F3 operator*(float s, F3 a) { return {s * a.x, s * a.y, s * a.z}; }
__device__ __forceinline__ float dot3(F3 a, F3 b) { return a.x * b.x + a.y * b.y + a.z * b.z; }
__device__ __forceinline__ F3 cross3(F3 a, F3 b) {
    return {a.y * b.z - a.z * b.y, a.z * b.x - a.x * b.z, a.x * b.y - a.y * b.x};
}

// load position j from the LDS-staged batch
__device__ __forceinline__ F3 ldl(const float4* sj, int j) {
    float4 t = sj[j];
    return {t.x, t.y, t.z};
}

// ---------------- bonded contributions (read positions from LDS) ----------------
__device__ __forceinline__ F3 bond_force(const float4* sj, int k, int side,
    const float* __restrict__ spring_k, const float* __restrict__ bond_d0,
    const int* __restrict__ bond_tid)
{
    F3 r = ldl(sj, k) - ldl(sj, k + 1);
    float d = sqrtf(dot3(r, r) + EPSF);
    int ty = bond_tid[k];
    float coef = -spring_k[ty] * (d - bond_d0[ty]) / d;
    return (side == 0 ? coef : -coef) * r;
}

__device__ __forceinline__ F3 angle_force(const float4* sj, int k, int p,
    const float* __restrict__ angle_k_arr, const float* __restrict__ angle_th0,
    const int* __restrict__ angle_tid)
{
    F3 p0 = ldl(sj, k), p1 = ldl(sj, k + 1), p2 = ldl(sj, k + 2);
    F3 u = p0 - p1, v = p2 - p1;
    float uu = dot3(u, u), vv = dot3(v, v), uv = dot3(u, v);
    float den = sqrtf(uu * vv + EPSF);
    float c = uv / den;
    const float lo = -1.f + 1e-6f, hi = 1.f - 1e-6f;
    float cl = fminf(fmaxf(c, lo), hi);
    float theta = acosf(cl);
    int ty = angle_tid[k];
    bool inr = (c > lo) && (c < hi);
    float g = inr ? (-angle_k_arr[ty] * (theta - angle_th0[ty]) * rsqrtf(1.f - cl * cl)) : 0.f;
    float invden = 1.f / den;
    float invden3 = invden * invden * invden;
    F3 dcdu = invden * v - (uv * vv * invden3) * u;
    F3 dcdv = invden * u - (uv * uu * invden3) * v;
    F3 F0 = (-g) * dcdu;
    F3 F2 = (-g) * dcdv;
    if (p == 0) return F0;
    if (p == 2) return F2;
    return mkf3(-(F0.x + F2.x), -(F0.y + F2.y), -(F0.z + F2.z));
}

__device__ __forceinline__ F3 dih_force(const float4* sj, int k, int p,
    const float* __restrict__ dih_k_arr, const float* __restrict__ dih_phi0,
    const int* __restrict__ dih_tid)
{
    F3 p0 = ldl(sj, k), p1 = ldl(sj, k + 1), p2 = ldl(sj, k + 2), p3 = ldl(sj, k + 3);
    F3 b1 = p1 - p0, b2 = p2 - p1, b3 = p3 - p2;
    F3 n1 = cross3(b1, b2), n2 = cross3(b2, b3);
    float L2 = dot3(b2, b2) + EPSF;
    float L = sqrtf(L2);
    F3 b2u = (1.f / L) * b2;
    F3 m1 = cross3(n1, b2u);
    float x = dot3(n1, n2), y = dot3(m1, n2);
    float phi = atan2f(y, x);
    int ty = dih_tid[k];
    float dEdphi = dih_k_arr[ty] * (phi - dih_phi0[ty]);
    float inv_xy = 1.f / (x * x + y * y);

    F3 gx_b1 = cross3(b2, n2);
    F3 gx_b2 = cross3(n2, b1) + cross3(b3, n1);
    F3 gx_b3 = cross3(n1, b2);
    F3 bun2 = cross3(b2u, n2);
    F3 gy_b1 = cross3(b2, bun2);
    F3 w = cross3(n2, n1);
    F3 gy_b2 = cross3(bun2, b1) + cross3(b3, m1) + (1.f / L) * (w - (dot3(b2, w) / L2) * b2);
    F3 gy_b3 = cross3(m1, b2);

    float cx = dEdphi * inv_xy;
    F3 dE_b1 = cx * (x * gy_b1 - y * gx_b1);
    F3 dE_b2 = cx * (x * gy_b2 - y * gx_b2);
    F3 dE_b3 = cx * (x * gy_b3 - y * gx_b3);
    if (p == 0) return dE_b1;
    if (p == 1) return dE_b2 - dE_b1;
    if (p == 2) return dE_b3 - dE_b2;
    return -dE_b3;
}

// ---------------- fully fused kernel: one dispatch, no atomics, no ws ----------------
// block = 256 threads = SL(8) j-slices x AT(32) atoms; stages the whole batch
// (pos+q, radii) in LDS, computes nb gather + bonded gather, coalesced store.
__global__ __launch_bounds__(NT) void fused_kernel(
    const float* __restrict__ pos, const float* __restrict__ bead_radii,
    const float* __restrict__ q_vals, const float* __restrict__ spring_k,
    const float* __restrict__ bond_d0, const float* __restrict__ angle_k,
    const float* __restrict__ angle_th0, const float* __restrict__ dih_k,
    const float* __restrict__ dih_phi0, const float* __restrict__ disp_k,
    const float* __restrict__ hbond_k, const float* __restrict__ e_r,
    const float* __restrict__ f_0, const int* __restrict__ bead_types,
    const int* __restrict__ charge_idx, const int* __restrict__ bond_tid,
    const int* __restrict__ angle_tid, const int* __restrict__ dih_tid,
    const int* __restrict__ nb_tid,
    float* __restrict__ out, int N, int n_nbt, int n_bt,
    int nbond, int nang, int ndih)
{
    __shared__ float4 sj[NMAX];       // x,y,z,q of the whole batch
    __shared__ float  srad[NMAX];     // per-atom radius (fallback path)
    __shared__ float  red[2 * SL][AT][3];
    __shared__ int    sflag;

    const int tid = threadIdx.x;
    const int b = blockIdx.y;
    const int i0 = blockIdx.x * AT;

    if (tid == 0) sflag = 1;
    __syncthreads();

    const float A0 = disp_k[0], B0 = hbond_k[0], R0 = bead_radii[0];
    for (int t = tid; t < n_nbt; t += NT)
        if (disp_k[t] != A0 || hbond_k[t] != B0) sflag = 0;
    if (tid < n_bt && bead_radii[tid] != R0) sflag = 0;

    // stage whole batch: pos(xyz) + q into float4, radius separately
    for (int j = tid; j < N; j += NT) {
        const float* pj = pos + ((size_t)b * N + j) * 3;
        sj[j] = make_float4(pj[0], pj[1], pj[2], q_vals[charge_idx[j]]);
        srad[j] = bead_radii[bead_types[j]];
    }
    __syncthreads();

    const bool uni = (sflag != 0);
    const int s = tid >> 5;           // slice / role id, 0..7
    const int a = tid & (AT - 1);     // local atom
    const int i = i0 + a;
    const int SLEN = N / SL;          // 256
    const int jbase = s * SLEN;

    const float f0e = f_0[0] / e_r[0];
    const float4 mine = sj[i];
    const float pix = mine.x, piy = mine.y, piz = mine.z;
    const float qis = f0e * mine.w;

    float fx = 0.f, fy = 0.f, fz = 0.f;

    if (uni) {
        const float sig2 = 4.f * R0 * R0;
        const float c6 = 6.f * B0, c12n = -12.f * A0;
        const int dj2b = jbase - i + 2;   // (j - i) + 2 at k = 0
#pragma unroll 8
        for (int k = 0; k < SLEN; ++k) {
            float4 pj = sj[jbase + k];
            float rx = pj.x - pix, ry = pj.y - piy, rz = pj.z - piz;
            float d2 = fmaf(rx, rx, fmaf(ry, ry, fmaf(rz, rz, EPSF)));
            float inv = __builtin_amdgcn_rsqf(d2);
            float inv2 = inv * inv;
            float sr2 = sig2 * inv2;
            float sr6 = sr2 * sr2 * sr2;
            float lj = sr6 * fmaf(c12n, sr6, c6);
            float sc = inv2 * fmaf(-qis * pj.w, inv, lj);
            bool val = ((unsigned)(dj2b + k)) > 4u;   // |j-i| >= 3
            sc = val ? sc : 0.f;
            fx = fmaf(sc, rx, fx); fy = fmaf(sc, ry, fy); fz = fmaf(sc, rz, fz);
        }
    } else {
        // generic fallback: per-pair type lookup (analytic upper-tri pair index)
        const float radi = srad[i];
        const int basei = i * (N - 3) - (i * (i - 1)) / 2;
        for (int k = 0; k < SLEN; ++k) {
            int j = jbase + k;
            int dj = j - i;
            if (((unsigned)(dj + 2)) > 4u) {
                int pidx = (dj > 0) ? (basei + dj - 3)
                                    : (j * (N - 3) - (j * (j - 1)) / 2 - dj - 3);
                int tt = nb_tid[pidx];
                float A = disp_k[tt], Bc = hbond_k[tt];
                float4 pj = sj[j];
                float rx = pj.x - pix, ry = pj.y - piy, rz = pj.z - piz;
                float d2 = fmaf(rx, rx, fmaf(ry, ry, fmaf(rz, rz, EPSF)));
                float inv = rsqrtf(d2);
                inv = inv * fmaf(-0.5f * d2 * inv, inv, 1.5f);
                float inv2 = inv * inv;
                float sig = radi + srad[j];
                float sr2 = sig * sig * inv2;
                float sr6 = sr2 * sr2 * sr2;
                float lj = sr6 * fmaf(-12.f * A, sr6, 6.f * Bc);
                float sc = inv2 * fmaf(-qis * pj.w, inv, lj);
                fx = fmaf(sc, rx, fx); fy = fmaf(sc, ry, fy); fz = fmaf(sc, rz, fz);
            }
        }
    }
    red[s][a][0] = fx; red[s][a][1] = fy; red[s][a][2] = fz;

    // ---- bonded terms: role s handles one contribution class for atom i,
    //      positions read from LDS. Roles packed 2-per-wave for divergence.
    F3 F = mkf3(0.f, 0.f, 0.f);
    if (s == 0) {
        if (i <= nbond - 1) F = F + bond_force(sj, i, 0, spring_k, bond_d0, bond_tid);
        if (i >= 1)         F = F + bond_force(sj, i - 1, 1, spring_k, bond_d0, bond_tid);
    } else if (s == 1) {
        if (i <= nang - 1)  F = angle_force(sj, i, 0, angle_k, angle_th0, angle_tid);
    } else if (s == 2) {
        if (i >= 1 && i - 1 <= nang - 1) F = angle_force(sj, i - 1, 1, angle_k, angle_th0, angle_tid);
    } else if (s == 3) {
        if (i >= 2 && i - 2 <= nang - 1) F = angle_force(sj, i - 2, 2, angle_k, angle_th0, angle_tid);
    } else if (s == 4) {
        if (i < ndih)                    F = dih_force(sj, i, 0, dih_k, dih_phi0, dih_tid);
    } else if (s == 5) {
        if (i >= 1 && i - 1 < ndih)      F = dih_force(sj, i - 1, 1, dih_k, dih_phi0, dih_tid);
    } else if (s == 6) {
        if (i >= 2 && i - 2 < ndih)      F = dih_force(sj, i - 2, 2, dih_k, dih_phi0, dih_tid);
    } else {
        if (i >= 3 && i - 3 < ndih)      F = dih_force(sj, i - 3, 3, dih_k, dih_phi0, dih_tid);
    }
    red[SL + s][a][0] = F.x; red[SL + s][a][1] = F.y; red[SL + s][a][2] = F.z;

    __syncthreads();

    // ---- final: 96 lanes sum 16 partial rows, fully coalesced store
    if (tid < AT * 3) {
        int aa = tid / 3, c = tid - 3 * aa;
        float v = 0.f;
#pragma unroll
        for (int r = 0; r < 2 * SL; ++r) v += red[r][aa][c];
        out[((size_t)b * N + i0) * 3 + tid] = v;
    }
}

extern "C" void kernel_launch(void* const* d_in, const int* in_sizes, int n_in,
                              void* d_out, int out_size, void* d_ws, size_t ws_size,
                              hipStream_t stream) {
    const float* pos = (const float*)d_in[0];
    const float* bead_radii = (const float*)d_in[1];
    const float* q_vals = (const float*)d_in[2];
    const float* spring_k = (const float*)d_in[3];
    const float* bond_d0 = (const float*)d_in[4];
    const float* angle_k = (const float*)d_in[5];
    const float* angle_th0 = (const float*)d_in[6];
    const float* dih_k = (const float*)d_in[7];
    const float* dih_phi0 = (const float*)d_in[8];
    const float* disp_k = (const float*)d_in[9];
    const float* hbond_k = (const float*)d_in[10];
    const float* e_r = (const float*)d_in[11];
    const float* f_0 = (const float*)d_in[12];
    const int* bead_types = (const int*)d_in[13];
    const int* charge_idx = (const int*)d_in[14];
    const int* bond_tid = (const int*)d_in[16];
    const int* angle_tid = (const int*)d_in[18];
    const int* dih_tid = (const int*)d_in[20];
    const int* nb_tid = (const int*)d_in[23];
    float* out = (float*)d_out;

    const int N = in_sizes[13];             // 2048
    const int B = in_sizes[0] / (N * 3);    // 4
    const int nbond = in_sizes[16];         // N-1
    const int nang = in_sizes[18];          // N-2
    const int ndih = in_sizes[20];          // 512
    const int n_nbt = in_sizes[9];          // 256
    const int n_bt = in_sizes[1];           // 16

    dim3 grid(N / AT, B);                   // (64, 4) = 256 blocks, 1 per CU
    fused_kernel<<<grid, NT, 0, stream>>>(
        pos, bead_radii, q_vals, spring_k, bond_d0, angle_k, angle_th0,
        dih_k, dih_phi0, disp_k, hbond_k, e_r, f_0,
        bead_types, charge_idx, bond_tid, angle_tid, dih_tid, nb_tid,
        out, N, n_nbt, n_bt, nbond, nang, ndih);
}

// Round 5
// 17.438 us; speedup vs baseline: 2.1433x; 1.1605x over previous
//
#include <hip/hip_runtime.h>
#include <math.h>

#define EPSF 1e-12f
#define NMAX 2048
#define AT 32            // atoms per block
#define NT 512           // threads per block (8 waves -> 2 waves/SIMD)
#define SL 16            // j-slices per block (NT/AT)

// ---------------- small float3 helpers ----------------
struct F3 { float x, y, z; };
__device__ __forceinline__ F3 mkf3(float a, float b, float c) { return {a, b, c}; }
__device__ __forceinline__ F3 operator-(F3 a, F3 b) { return {a.x - b.x, a.y - b.y, a.z - b.z}; }
__device__ __forceinline__ F3 operator+(F3 a, F3 b) { return {a.x + b.x, a.y + b.y, a.z + b.z}; }
__device__ __forceinline__ F3 operator-(F3 a) { return {-a.x, -a.y, -a.z}; }
__device__ __forceinline__ F3 operator*(float s, F3 a) { return {s * a.x, s * a.y, s * a.z}; }
__device__ __forceinline__ float dot3(F3 a, F3 b) { return a.x * b.x + a.y * b.y + a.z * b.z; }
__device__ __forceinline__ F3 cross3(F3 a, F3 b) {
    return {a.y * b.z - a.z * b.y, a.z * b.x - a.x * b.z, a.x * b.y - a.y * b.x};
}
__device__ __forceinline__ F3 ldl(const float4* sj, int j) {
    float4 t = sj[j];
    return {t.x, t.y, t.z};
}

// ---------------- bonded contributions (positions from LDS) ----------------
__device__ __forceinline__ F3 bond_force(const float4* sj, int k, int side,
    const float* __restrict__ spring_k, const float* __restrict__ bond_d0,
    const int* __restrict__ bond_tid)
{
    F3 r = ldl(sj, k) - ldl(sj, k + 1);
    float d = sqrtf(dot3(r, r) + EPSF);
    int ty = bond_tid[k];
    float coef = -spring_k[ty] * (d - bond_d0[ty]) / d;
    return (side == 0 ? coef : -coef) * r;
}

__device__ __forceinline__ F3 angle_force(const float4* sj, int k, int p,
    const float* __restrict__ angle_k_arr, const float* __restrict__ angle_th0,
    const int* __restrict__ angle_tid)
{
    F3 p0 = ldl(sj, k), p1 = ldl(sj, k + 1), p2 = ldl(sj, k + 2);
    F3 u = p0 - p1, v = p2 - p1;
    float uu = dot3(u, u), vv = dot3(v, v), uv = dot3(u, v);
    float den = sqrtf(uu * vv + EPSF);
    float c = uv / den;
    const float lo = -1.f + 1e-6f, hi = 1.f - 1e-6f;
    float cl = fminf(fmaxf(c, lo), hi);
    float theta = acosf(cl);
    int ty = angle_tid[k];
    bool inr = (c > lo) && (c < hi);
    float g = inr ? (-angle_k_arr[ty] * (theta - angle_th0[ty]) * rsqrtf(1.f - cl * cl)) : 0.f;
    float invden = 1.f / den;
    float invden3 = invden * invden * invden;
    F3 dcdu = invden * v - (uv * vv * invden3) * u;
    F3 dcdv = invden * u - (uv * uu * invden3) * v;
    F3 F0 = (-g) * dcdu;
    F3 F2 = (-g) * dcdv;
    if (p == 0) return F0;
    if (p == 2) return F2;
    return mkf3(-(F0.x + F2.x), -(F0.y + F2.y), -(F0.z + F2.z));
}

__device__ __forceinline__ F3 dih_force(const float4* sj, int k, int p,
    const float* __restrict__ dih_k_arr, const float* __restrict__ dih_phi0,
    const int* __restrict__ dih_tid)
{
    F3 p0 = ldl(sj, k), p1 = ldl(sj, k + 1), p2 = ldl(sj, k + 2), p3 = ldl(sj, k + 3);
    F3 b1 = p1 - p0, b2 = p2 - p1, b3 = p3 - p2;
    F3 n1 = cross3(b1, b2), n2 = cross3(b2, b3);
    float L2 = dot3(b2, b2) + EPSF;
    float L = sqrtf(L2);
    F3 b2u = (1.f / L) * b2;
    F3 m1 = cross3(n1, b2u);
    float x = dot3(n1, n2), y = dot3(m1, n2);
    float phi = atan2f(y, x);
    int ty = dih_tid[k];
    float dEdphi = dih_k_arr[ty] * (phi - dih_phi0[ty]);
    float inv_xy = 1.f / (x * x + y * y);

    F3 gx_b1 = cross3(b2, n2);
    F3 gx_b2 = cross3(n2, b1) + cross3(b3, n1);
    F3 gx_b3 = cross3(n1, b2);
    F3 bun2 = cross3(b2u, n2);
    F3 gy_b1 = cross3(b2, bun2);
    F3 w = cross3(n2, n1);
    F3 gy_b2 = cross3(bun2, b1) + cross3(b3, m1) + (1.f / L) * (w - (dot3(b2, w) / L2) * b2);
    F3 gy_b3 = cross3(m1, b2);

    float cx = dEdphi * inv_xy;
    F3 dE_b1 = cx * (x * gy_b1 - y * gx_b1);
    F3 dE_b2 = cx * (x * gy_b2 - y * gx_b2);
    F3 dE_b3 = cx * (x * gy_b3 - y * gx_b3);
    if (p == 0) return dE_b1;
    if (p == 1) return dE_b2 - dE_b1;
    if (p == 2) return dE_b3 - dE_b2;
    return -dE_b3;
}

// ---------------- fully fused kernel: one dispatch, no atomics, no ws ----------------
__global__ __launch_bounds__(NT) void fused_kernel(
    const float* __restrict__ pos, const float* __restrict__ bead_radii,
    const float* __restrict__ q_vals, const float* __restrict__ spring_k,
    const float* __restrict__ bond_d0, const float* __restrict__ angle_k,
    const float* __restrict__ angle_th0, const float* __restrict__ dih_k,
    const float* __restrict__ dih_phi0, const float* __restrict__ disp_k,
    const float* __restrict__ hbond_k, const float* __restrict__ e_r,
    const float* __restrict__ f_0, const int* __restrict__ bead_types,
    const int* __restrict__ charge_idx, const int* __restrict__ bond_tid,
    const int* __restrict__ angle_tid, const int* __restrict__ dih_tid,
    const int* __restrict__ nb_tid,
    float* __restrict__ out, int N, int n_nbt, int n_bt,
    int nbond, int nang, int ndih)
{
    __shared__ float4 sj[NMAX];        // x,y,z,q of the whole batch
    __shared__ float  srad[NMAX];      // only filled on fallback path
    __shared__ float  red[SL + 8][AT][3];
    __shared__ int    sflag;

    const int tid = threadIdx.x;
    const int b = blockIdx.y;
    const int i0 = blockIdx.x * AT;

    if (tid == 0) sflag = 1;
    __syncthreads();

    const float A0 = disp_k[0], B0 = hbond_k[0], R0 = bead_radii[0];
    for (int t = tid; t < n_nbt; t += NT)
        if (disp_k[t] != A0 || hbond_k[t] != B0) sflag = 0;
    if (tid < n_bt && bead_radii[tid] != R0) sflag = 0;

    // stage whole batch: pos(xyz) + q into float4
    for (int j = tid; j < N; j += NT) {
        const float* pj = pos + ((size_t)b * N + j) * 3;
        sj[j] = make_float4(pj[0], pj[1], pj[2], q_vals[charge_idx[j]]);
    }
    __syncthreads();

    const bool uni = (sflag != 0);
    const int s = tid >> 5;            // slice id, 0..15 (32-lane group)
    const int a = tid & (AT - 1);      // local atom
    const int i = i0 + a;
    const int SLEN = N / SL;           // 128
    const int jbase = s * SLEN;

    const float f0e = f_0[0] / e_r[0];
    const float4 mine = sj[i];
    const float pix = mine.x, piy = mine.y, piz = mine.z;
    const float nqis = -f0e * mine.w;

    float fx = 0.f, fy = 0.f, fz = 0.f;

    if (uni) {
        const float sig2 = 4.f * R0 * R0;
        const float c6 = 6.f * B0, c12n = -12.f * A0;
        // wave-uniform: does this wave's j-range touch the exclusion window?
        const int wbase = (s & ~1) * SLEN;          // wave covers [wbase, wbase+2*SLEN)
        const bool needMask = (wbase <= i0 + AT + 1) && (i0 - 2 < wbase + 2 * SLEN);
        if (!needMask) {
#pragma unroll 8
            for (int k = 0; k < SLEN; ++k) {
                float4 pj = sj[jbase + k];
                float rx = pj.x - pix, ry = pj.y - piy, rz = pj.z - piz;
                float d2 = fmaf(rx, rx, fmaf(ry, ry, fmaf(rz, rz, EPSF)));
                float inv = __builtin_amdgcn_rsqf(d2);
                float inv2 = inv * inv;
                float sr2 = sig2 * inv2;
                float sr6 = sr2 * sr2 * sr2;
                float lj = sr6 * fmaf(c12n, sr6, c6);
                float sc = inv2 * fmaf(nqis * pj.w, inv, lj);
                fx = fmaf(sc, rx, fx); fy = fmaf(sc, ry, fy); fz = fmaf(sc, rz, fz);
            }
        } else {
            const int dj2b = jbase - i + 2;         // (j-i)+2 at k=0
#pragma unroll 8
            for (int k = 0; k < SLEN; ++k) {
                float4 pj = sj[jbase + k];
                float rx = pj.x - pix, ry = pj.y - piy, rz = pj.z - piz;
                float d2 = fmaf(rx, rx, fmaf(ry, ry, fmaf(rz, rz, EPSF)));
                float inv = __builtin_amdgcn_rsqf(d2);
                float inv2 = inv * inv;
                float sr2 = sig2 * inv2;
                float sr6 = sr2 * sr2 * sr2;
                float lj = sr6 * fmaf(c12n, sr6, c6);
                float sc = inv2 * fmaf(nqis * pj.w, inv, lj);
                bool val = ((unsigned)(dj2b + k)) > 4u;   // |j-i| >= 3
                sc = val ? sc : 0.f;
                fx = fmaf(sc, rx, fx); fy = fmaf(sc, ry, fy); fz = fmaf(sc, rz, fz);
            }
        }
    } else {
        // generic fallback (block-uniform branch): per-pair type lookup
        for (int j = tid; j < N; j += NT)
            srad[j] = bead_radii[bead_types[j]];
        __syncthreads();
        const float radi = srad[i];
        const int basei = i * (N - 3) - (i * (i - 1)) / 2;
        for (int k = 0; k < SLEN; ++k) {
            int j = jbase + k;
            int dj = j - i;
            if (((unsigned)(dj + 2)) > 4u) {
                int pidx = (dj > 0) ? (basei + dj - 3)
                                    : (j * (N - 3) - (j * (j - 1)) / 2 - dj - 3);
                int tt = nb_tid[pidx];
                float A = disp_k[tt], Bc = hbond_k[tt];
                float4 pj = sj[j];
                float rx = pj.x - pix, ry = pj.y - piy, rz = pj.z - piz;
                float d2 = fmaf(rx, rx, fmaf(ry, ry, fmaf(rz, rz, EPSF)));
                float inv = rsqrtf(d2);
                inv = inv * fmaf(-0.5f * d2 * inv, inv, 1.5f);
                float inv2 = inv * inv;
                float sig = radi + srad[j];
                float sr2 = sig * sig * inv2;
                float sr6 = sr2 * sr2 * sr2;
                float lj = sr6 * fmaf(-12.f * A, sr6, 6.f * Bc);
                float sc = inv2 * fmaf(nqis * pj.w, inv, lj);
                fx = fmaf(sc, rx, fx); fy = fmaf(sc, ry, fy); fz = fmaf(sc, rz, fz);
            }
        }
    }
    red[s][a][0] = fx; red[s][a][1] = fy; red[s][a][2] = fz;

    // ---- bonded terms: groups 8..15 each take one contribution class
    if (s >= 8) {
        const int r = s - 8;
        F3 F = mkf3(0.f, 0.f, 0.f);
        if (r == 0) {
            if (i <= nbond - 1) F = F + bond_force(sj, i, 0, spring_k, bond_d0, bond_tid);
            if (i >= 1)         F = F + bond_force(sj, i - 1, 1, spring_k, bond_d0, bond_tid);
        } else if (r == 1) {
            if (i <= nang - 1)               F = angle_force(sj, i, 0, angle_k, angle_th0, angle_tid);
        } else if (r == 2) {
            if (i >= 1 && i - 1 <= nang - 1) F = angle_force(sj, i - 1, 1, angle_k, angle_th0, angle_tid);
        } else if (r == 3) {
            if (i >= 2 && i - 2 <= nang - 1) F = angle_force(sj, i - 2, 2, angle_k, angle_th0, angle_tid);
        } else if (r == 4) {
            if (i < ndih)                    F = dih_force(sj, i, 0, dih_k, dih_phi0, dih_tid);
        } else if (r == 5) {
            if (i >= 1 && i - 1 < ndih)      F = dih_force(sj, i - 1, 1, dih_k, dih_phi0, dih_tid);
        } else if (r == 6) {
            if (i >= 2 && i - 2 < ndih)      F = dih_force(sj, i - 2, 2, dih_k, dih_phi0, dih_tid);
        } else {
            if (i >= 3 && i - 3 < ndih)      F = dih_force(sj, i - 3, 3, dih_k, dih_phi0, dih_tid);
        }
        red[SL + r][a][0] = F.x; red[SL + r][a][1] = F.y; red[SL + r][a][2] = F.z;
    }

    __syncthreads();

    // ---- final: 96 lanes sum SL+8 partial rows, fully coalesced store
    if (tid < AT * 3) {
        int aa = tid / 3, c = tid - 3 * aa;
        float v = 0.f;
#pragma unroll
        for (int r = 0; r < SL + 8; ++r) v += red[r][aa][c];
        out[((size_t)b * N + i0) * 3 + tid] = v;
    }
}

extern "C" void kernel_launch(void* const* d_in, const int* in_sizes, int n_in,
                              void* d_out, int out_size, void* d_ws, size_t ws_size,
                              hipStream_t stream) {
    const float* pos = (const float*)d_in[0];
    const float* bead_radii = (const float*)d_in[1];
    const float* q_vals = (const float*)d_in[2];
    const float* spring_k = (const float*)d_in[3];
    const float* bond_d0 = (const float*)d_in[4];
    const float* angle_k = (const float*)d_in[5];
    const float* angle_th0 = (const float*)d_in[6];
    const float* dih_k = (const float*)d_in[7];
    const float* dih_phi0 = (const float*)d_in[8];
    const float* disp_k = (const float*)d_in[9];
    const float* hbond_k = (const float*)d_in[10];
    const float* e_r = (const float*)d_in[11];
    const float* f_0 = (const float*)d_in[12];
    const int* bead_types = (const int*)d_in[13];
    const int* charge_idx = (const int*)d_in[14];
    const int* bond_tid = (const int*)d_in[16];
    const int* angle_tid = (const int*)d_in[18];
    const int* dih_tid = (const int*)d_in[20];
    const int* nb_tid = (const int*)d_in[23];
    float* out = (float*)d_out;

    const int N = in_sizes[13];             // 2048
    const int B = in_sizes[0] / (N * 3);    // 4
    const int nbond = in_sizes[16];         // N-1
    const int nang = in_sizes[18];          // N-2
    const int ndih = in_sizes[20];          // 512
    const int n_nbt = in_sizes[9];          // 256
    const int n_bt = in_sizes[1];           // 16

    dim3 grid(N / AT, B);                   // (64, 4) = 256 blocks, 1 per CU
    fused_kernel<<<grid, NT, 0, stream>>>(
        pos, bead_radii, q_vals, spring_k, bond_d0, angle_k, angle_th0,
        dih_k, dih_phi0, disp_k, hbond_k, e_r, f_0,
        bead_types, charge_idx, bond_tid, angle_tid, dih_tid, nb_tid,
        out, N, n_nbt, n_bt, nbond, nang, ndih);
}

// Round 6
// 17.050 us; speedup vs baseline: 2.1920x; 1.0227x over previous
//
#include <hip/hip_runtime.h>
#include <math.h>

#define EPSF 1e-12f
#define NMAX 2048
#define AT 32            // atoms per block
#define NT 1024          // threads per block (16 waves -> 4 waves/SIMD)
#define SL 32            // j-slices per block (NT/AT)

// ---------------- small float3 helpers ----------------
struct F3 { float x, y, z; };
__device__ __forceinline__ F3 mkf3(float a, float b, float c) { return {a, b, c}; }
__device__ __forceinline__ F3 operator-(F3 a, F3 b) { return {a.x - b.x, a.y - b.y, a.z - b.z}; }
__device__ __forceinline__ F3 operator+(F3 a, F3 b) { return {a.x + b.x, a.y + b.y, a.z + b.z}; }
__device__ __forceinline__ F3 operator-(F3 a) { return {-a.x, -a.y, -a.z}; }
__device__ __forceinline__ F3 operator*(float s, F3 a) { return {s * a.x, s * a.y, s * a.z}; }
__device__ __forceinline__ float dot3(F3 a, F3 b) { return a.x * b.x + a.y * b.y + a.z * b.z; }
__device__ __forceinline__ F3 cross3(F3 a, F3 b) {
    return {a.y * b.z - a.z * b.y, a.z * b.x - a.x * b.z, a.x * b.y - a.y * b.x};
}
__device__ __forceinline__ F3 ldl(const float4* sj, int j) {
    float4 t = sj[j];
    return {t.x, t.y, t.z};
}

// ---------------- bonded contributions (positions from LDS) ----------------
__device__ __forceinline__ F3 bond_force(const float4* sj, int k, int side,
    const float* __restrict__ spring_k, const float* __restrict__ bond_d0,
    const int* __restrict__ bond_tid)
{
    F3 r = ldl(sj, k) - ldl(sj, k + 1);
    float d = sqrtf(dot3(r, r) + EPSF);
    int ty = bond_tid[k];
    float coef = -spring_k[ty] * (d - bond_d0[ty]) / d;
    return (side == 0 ? coef : -coef) * r;
}

__device__ __forceinline__ F3 angle_force(const float4* sj, int k, int p,
    const float* __restrict__ angle_k_arr, const float* __restrict__ angle_th0,
    const int* __restrict__ angle_tid)
{
    F3 p0 = ldl(sj, k), p1 = ldl(sj, k + 1), p2 = ldl(sj, k + 2);
    F3 u = p0 - p1, v = p2 - p1;
    float uu = dot3(u, u), vv = dot3(v, v), uv = dot3(u, v);
    float den = sqrtf(uu * vv + EPSF);
    float c = uv / den;
    const float lo = -1.f + 1e-6f, hi = 1.f - 1e-6f;
    float cl = fminf(fmaxf(c, lo), hi);
    float theta = acosf(cl);
    int ty = angle_tid[k];
    bool inr = (c > lo) && (c < hi);
    float g = inr ? (-angle_k_arr[ty] * (theta - angle_th0[ty]) * rsqrtf(1.f - cl * cl)) : 0.f;
    float invden = 1.f / den;
    float invden3 = invden * invden * invden;
    F3 dcdu = invden * v - (uv * vv * invden3) * u;
    F3 dcdv = invden * u - (uv * uu * invden3) * v;
    F3 F0 = (-g) * dcdu;
    F3 F2 = (-g) * dcdv;
    if (p == 0) return F0;
    if (p == 2) return F2;
    return mkf3(-(F0.x + F2.x), -(F0.y + F2.y), -(F0.z + F2.z));
}

__device__ __forceinline__ F3 dih_force(const float4* sj, int k, int p,
    const float* __restrict__ dih_k_arr, const float* __restrict__ dih_phi0,
    const int* __restrict__ dih_tid)
{
    F3 p0 = ldl(sj, k), p1 = ldl(sj, k + 1), p2 = ldl(sj, k + 2), p3 = ldl(sj, k + 3);
    F3 b1 = p1 - p0, b2 = p2 - p1, b3 = p3 - p2;
    F3 n1 = cross3(b1, b2), n2 = cross3(b2, b3);
    float L2 = dot3(b2, b2) + EPSF;
    float L = sqrtf(L2);
    F3 b2u = (1.f / L) * b2;
    F3 m1 = cross3(n1, b2u);
    float x = dot3(n1, n2), y = dot3(m1, n2);
    float phi = atan2f(y, x);
    int ty = dih_tid[k];
    float dEdphi = dih_k_arr[ty] * (phi - dih_phi0[ty]);
    float inv_xy = 1.f / (x * x + y * y);

    F3 gx_b1 = cross3(b2, n2);
    F3 gx_b2 = cross3(n2, b1) + cross3(b3, n1);
    F3 gx_b3 = cross3(n1, b2);
    F3 bun2 = cross3(b2u, n2);
    F3 gy_b1 = cross3(b2, bun2);
    F3 w = cross3(n2, n1);
    F3 gy_b2 = cross3(bun2, b1) + cross3(b3, m1) + (1.f / L) * (w - (dot3(b2, w) / L2) * b2);
    F3 gy_b3 = cross3(m1, b2);

    float cx = dEdphi * inv_xy;
    F3 dE_b1 = cx * (x * gy_b1 - y * gx_b1);
    F3 dE_b2 = cx * (x * gy_b2 - y * gx_b2);
    F3 dE_b3 = cx * (x * gy_b3 - y * gx_b3);
    if (p == 0) return dE_b1;
    if (p == 1) return dE_b2 - dE_b1;
    if (p == 2) return dE_b3 - dE_b2;
    return -dE_b3;
}

// ---------------- fully fused kernel: one dispatch, no atomics, no ws ----------------
__global__ __launch_bounds__(NT) void fused_kernel(
    const float* __restrict__ pos, const float* __restrict__ bead_radii,
    const float* __restrict__ q_vals, const float* __restrict__ spring_k,
    const float* __restrict__ bond_d0, const float* __restrict__ angle_k,
    const float* __restrict__ angle_th0, const float* __restrict__ dih_k,
    const float* __restrict__ dih_phi0, const float* __restrict__ disp_k,
    const float* __restrict__ hbond_k, const float* __restrict__ e_r,
    const float* __restrict__ f_0, const int* __restrict__ bead_types,
    const int* __restrict__ charge_idx, const int* __restrict__ bond_tid,
    const int* __restrict__ angle_tid, const int* __restrict__ dih_tid,
    const int* __restrict__ nb_tid,
    float* __restrict__ out, int N, int n_nbt, int n_bt,
    int nbond, int nang, int ndih)
{
    __shared__ float4 sj[NMAX];        // x,y,z,q of the whole batch
    __shared__ float  srad[NMAX];      // only filled on fallback path
    __shared__ float  red[SL + 8][AT][3];
    __shared__ int    sflag;

    const int tid = threadIdx.x;
    const int b = blockIdx.y;
    const int i0 = blockIdx.x * AT;

    if (tid == 0) sflag = 1;
    __syncthreads();

    const float A0 = disp_k[0], B0 = hbond_k[0], R0 = bead_radii[0];
    for (int t = tid; t < n_nbt; t += NT)
        if (disp_k[t] != A0 || hbond_k[t] != B0) sflag = 0;
    if (tid < n_bt && bead_radii[tid] != R0) sflag = 0;

    // stage whole batch: pos(xyz) + q into float4
    for (int j = tid; j < N; j += NT) {
        const float* pj = pos + ((size_t)b * N + j) * 3;
        sj[j] = make_float4(pj[0], pj[1], pj[2], q_vals[charge_idx[j]]);
    }
    __syncthreads();

    const bool uni = (sflag != 0);
    const int s = tid >> 5;            // slice id, 0..31 (32-lane group)
    const int a = tid & (AT - 1);      // local atom
    const int i = i0 + a;
    const int SLEN = N / SL;           // 64
    const int jbase = s * SLEN;

    const float f0e = f_0[0] / e_r[0];
    const float4 mine = sj[i];
    const float pix = mine.x, piy = mine.y, piz = mine.z;
    const float nqis = -f0e * mine.w;

    float fx = 0.f, fy = 0.f, fz = 0.f;

    if (uni) {
        // constant-folded LJ: sr6 = (sig2*u)^3 -> lj = u3*fma(K12, u3, K6)
        const float sig2 = 4.f * R0 * R0;
        const float s2_3 = sig2 * sig2 * sig2;
        const float K6 = 6.f * B0 * s2_3;
        const float K12 = -12.f * A0 * s2_3 * s2_3;
        // wave-uniform: does this wave's 2-slice j-range touch the exclusion window?
        const int wbase = (s & ~1) * SLEN;          // wave covers [wbase, wbase+2*SLEN)
        const bool needMask = (wbase <= i0 + AT + 1) && (i0 - 2 < wbase + 2 * SLEN);
        if (!needMask) {
#pragma unroll 8
            for (int k = 0; k < SLEN; ++k) {
                float4 pj = sj[jbase + k];
                float rx = pj.x - pix, ry = pj.y - piy, rz = pj.z - piz;
                float d2 = fmaf(rx, rx, fmaf(ry, ry, fmaf(rz, rz, EPSF)));
                float inv = __builtin_amdgcn_rsqf(d2);
                float u = inv * inv;
                float u3 = u * u * u;
                float lj = u3 * fmaf(K12, u3, K6);
                float sc = u * fmaf(nqis * pj.w, inv, lj);
                fx = fmaf(sc, rx, fx); fy = fmaf(sc, ry, fy); fz = fmaf(sc, rz, fz);
            }
        } else {
            const int dj2b = jbase - i + 2;         // (j-i)+2 at k=0
#pragma unroll 8
            for (int k = 0; k < SLEN; ++k) {
                float4 pj = sj[jbase + k];
                float rx = pj.x - pix, ry = pj.y - piy, rz = pj.z - piz;
                float d2 = fmaf(rx, rx, fmaf(ry, ry, fmaf(rz, rz, EPSF)));
                float inv = __builtin_amdgcn_rsqf(d2);
                float u = inv * inv;
                float u3 = u * u * u;
                float lj = u3 * fmaf(K12, u3, K6);
                float sc = u * fmaf(nqis * pj.w, inv, lj);
                bool val = ((unsigned)(dj2b + k)) > 4u;   // |j-i| >= 3
                sc = val ? sc : 0.f;
                fx = fmaf(sc, rx, fx); fy = fmaf(sc, ry, fy); fz = fmaf(sc, rz, fz);
            }
        }
    } else {
        // generic fallback (block-uniform branch): per-pair type lookup
        for (int j = tid; j < N; j += NT)
            srad[j] = bead_radii[bead_types[j]];
        __syncthreads();
        const float radi = srad[i];
        const int basei = i * (N - 3) - (i * (i - 1)) / 2;
        for (int k = 0; k < SLEN; ++k) {
            int j = jbase + k;
            int dj = j - i;
            if (((unsigned)(dj + 2)) > 4u) {
                int pidx = (dj > 0) ? (basei + dj - 3)
                                    : (j * (N - 3) - (j * (j - 1)) / 2 - dj - 3);
                int tt = nb_tid[pidx];
                float A = disp_k[tt], Bc = hbond_k[tt];
                float4 pj = sj[j];
                float rx = pj.x - pix, ry = pj.y - piy, rz = pj.z - piz;
                float d2 = fmaf(rx, rx, fmaf(ry, ry, fmaf(rz, rz, EPSF)));
                float inv = rsqrtf(d2);
                inv = inv * fmaf(-0.5f * d2 * inv, inv, 1.5f);
                float inv2 = inv * inv;
                float sig = radi + srad[j];
                float sr2 = sig * sig * inv2;
                float sr6 = sr2 * sr2 * sr2;
                float lj = sr6 * fmaf(-12.f * A, sr6, 6.f * Bc);
                float sc = inv2 * fmaf(nqis * pj.w, inv, lj);
                fx = fmaf(sc, rx, fx); fy = fmaf(sc, ry, fy); fz = fmaf(sc, rz, fz);
            }
        }
    }
    red[s][a][0] = fx; red[s][a][1] = fy; red[s][a][2] = fz;

    // ---- bonded terms: groups 24..31 each take one contribution class
    if (s >= SL - 8) {
        const int r = s - (SL - 8);
        F3 F = mkf3(0.f, 0.f, 0.f);
        if (r == 0) {
            if (i <= nbond - 1) F = F + bond_force(sj, i, 0, spring_k, bond_d0, bond_tid);
            if (i >= 1)         F = F + bond_force(sj, i - 1, 1, spring_k, bond_d0, bond_tid);
        } else if (r == 1) {
            if (i <= nang - 1)               F = angle_force(sj, i, 0, angle_k, angle_th0, angle_tid);
        } else if (r == 2) {
            if (i >= 1 && i - 1 <= nang - 1) F = angle_force(sj, i - 1, 1, angle_k, angle_th0, angle_tid);
        } else if (r == 3) {
            if (i >= 2 && i - 2 <= nang - 1) F = angle_force(sj, i - 2, 2, angle_k, angle_th0, angle_tid);
        } else if (r == 4) {
            if (i < ndih)                    F = dih_force(sj, i, 0, dih_k, dih_phi0, dih_tid);
        } else if (r == 5) {
            if (i >= 1 && i - 1 < ndih)      F = dih_force(sj, i - 1, 1, dih_k, dih_phi0, dih_tid);
        } else if (r == 6) {
            if (i >= 2 && i - 2 < ndih)      F = dih_force(sj, i - 2, 2, dih_k, dih_phi0, dih_tid);
        } else {
            if (i >= 3 && i - 3 < ndih)      F = dih_force(sj, i - 3, 3, dih_k, dih_phi0, dih_tid);
        }
        red[SL + r][a][0] = F.x; red[SL + r][a][1] = F.y; red[SL + r][a][2] = F.z;
    }

    __syncthreads();

    // ---- final: 96 lanes sum SL+8 partial rows, fully coalesced store
    if (tid < AT * 3) {
        int aa = tid / 3, c = tid - 3 * aa;
        float v = 0.f;
#pragma unroll
        for (int r = 0; r < SL + 8; ++r) v += red[r][aa][c];
        out[((size_t)b * N + i0) * 3 + tid] = v;
    }
}

extern "C" void kernel_launch(void* const* d_in, const int* in_sizes, int n_in,
                              void* d_out, int out_size, void* d_ws, size_t ws_size,
                              hipStream_t stream) {
    const float* pos = (const float*)d_in[0];
    const float* bead_radii = (const float*)d_in[1];
    const float* q_vals = (const float*)d_in[2];
    const float* spring_k = (const float*)d_in[3];
    const float* bond_d0 = (const float*)d_in[4];
    const float* angle_k = (const float*)d_in[5];
    const float* angle_th0 = (const float*)d_in[6];
    const float* dih_k = (const float*)d_in[7];
    const float* dih_phi0 = (const float*)d_in[8];
    const float* disp_k = (const float*)d_in[9];
    const float* hbond_k = (const float*)d_in[10];
    const float* e_r = (const float*)d_in[11];
    const float* f_0 = (const float*)d_in[12];
    const int* bead_types = (const int*)d_in[13];
    const int* charge_idx = (const int*)d_in[14];
    const int* bond_tid = (const int*)d_in[16];
    const int* angle_tid = (const int*)d_in[18];
    const int* dih_tid = (const int*)d_in[20];
    const int* nb_tid = (const int*)d_in[23];
    float* out = (float*)d_out;

    const int N = in_sizes[13];             // 2048
    const int B = in_sizes[0] / (N * 3);    // 4
    const int nbond = in_sizes[16];         // N-1
    const int nang = in_sizes[18];          // N-2
    const int ndih = in_sizes[20];          // 512
    const int n_nbt = in_sizes[9];          // 256
    const int n_bt = in_sizes[1];           // 16

    dim3 grid(N / AT, B);                   // (64, 4) = 256 blocks, 1 per CU
    fused_kernel<<<grid, NT, 0, stream>>>(
        pos, bead_radii, q_vals, spring_k, bond_d0, angle_k, angle_th0,
        dih_k, dih_phi0, disp_k, hbond_k, e_r, f_0,
        bead_types, charge_idx, bond_tid, angle_tid, dih_tid, nb_tid,
        out, N, n_nbt, n_bt, nbond, nang, ndih);
}